// Round 1
// baseline (616.979 us; speedup 1.0000x reference)
//
#include <hip/hip_runtime.h>

// VQ-VAE codebook quantization, MI355X (gfx950).
// N=65536 points, C=64 dims, K=4096 codes. Pure fp32 (no fp32 MFMA on CDNA4).
// Strategy: thread-per-point; codebook rows are wave-uniform -> compiler
// emits s_load (SMEM pipe) + SGPR-operand v_fmac, keeping VALU as the only
// saturated pipe. K split 4-ways (blockIdx.y) for 16 waves/CU occupancy.

#define NPTS   65536
#define CDIM   64
#define KCODES 4096
#define SPLITS 4
#define KPER   (KCODES / SPLITS)

__global__ __launch_bounds__(256) void vq_esq(const float* __restrict__ cb,
                                              float* __restrict__ esq) {
    int k = blockIdx.x * blockDim.x + threadIdx.x;
    if (k >= KCODES) return;
    const float4* p = reinterpret_cast<const float4*>(cb + (size_t)k * CDIM);
    float s0 = 0.f, s1 = 0.f, s2 = 0.f, s3 = 0.f;
#pragma unroll
    for (int i = 0; i < CDIM / 4; ++i) {
        float4 v = p[i];
        s0 = fmaf(v.x, v.x, s0);
        s1 = fmaf(v.y, v.y, s1);
        s2 = fmaf(v.z, v.z, s2);
        s3 = fmaf(v.w, v.w, s3);
    }
    esq[k] = (s0 + s1) + (s2 + s3);
}

__global__ __launch_bounds__(256) void vq_scan(const float* __restrict__ enc,
                                               const float* __restrict__ cb,
                                               const float* __restrict__ esq,
                                               float* __restrict__ pbest,
                                               int* __restrict__ pidx) {
    int n = blockIdx.x * 256 + threadIdx.x;
    int split = blockIdx.y;
    int k0 = split * KPER;

    // Point vector into registers (64 VGPRs).
    float x[CDIM];
    const float4* xp = reinterpret_cast<const float4*>(enc + (size_t)n * CDIM);
#pragma unroll
    for (int i = 0; i < CDIM / 4; ++i) {
        float4 v = xp[i];
        x[4 * i + 0] = v.x;
        x[4 * i + 1] = v.y;
        x[4 * i + 2] = v.z;
        x[4 * i + 3] = v.w;
    }

    float best = __builtin_inff();
    int bi = k0;
    const float* e = cb + (size_t)k0 * CDIM;  // wave-uniform pointer
    for (int kk = 0; kk < KPER; ++kk) {
        // 64 FMAs, 4 independent accumulator chains for ILP.
        float a0 = 0.f, a1 = 0.f, a2 = 0.f, a3 = 0.f;
#pragma unroll
        for (int d = 0; d < CDIM; d += 4) {
            a0 = fmaf(x[d + 0], e[d + 0], a0);
            a1 = fmaf(x[d + 1], e[d + 1], a1);
            a2 = fmaf(x[d + 2], e[d + 2], a2);
            a3 = fmaf(x[d + 3], e[d + 3], a3);
        }
        float score = fmaf(-2.f, (a0 + a1) + (a2 + a3), esq[k0 + kk]);
        if (score < best) { best = score; bi = k0 + kk; }  // strict < = first-index tie-break
        e += CDIM;
    }
    pbest[(size_t)split * NPTS + n] = best;
    pidx[(size_t)split * NPTS + n] = bi;
}

__global__ __launch_bounds__(256) void vq_finalize(const float* __restrict__ cb,
                                                   const float* __restrict__ pbest,
                                                   const int* __restrict__ pidx,
                                                   float* __restrict__ out) {
    int n = blockIdx.x * 256 + threadIdx.x;
    float best = __builtin_inff();
    int bi = 0;
#pragma unroll
    for (int s = 0; s < SPLITS; ++s) {
        // Ascending split order + strict < keeps the smallest index on exact ties,
        // matching jnp.argmin's first-occurrence semantics.
        float b = pbest[(size_t)s * NPTS + n];
        int i = pidx[(size_t)s * NPTS + n];
        if (b < best) { best = b; bi = i; }
    }
    const float4* e = reinterpret_cast<const float4*>(cb + (size_t)bi * CDIM);
    float4* o = reinterpret_cast<float4*>(out + (size_t)n * CDIM);
#pragma unroll
    for (int i = 0; i < CDIM / 4; ++i) o[i] = e[i];  // out value == q
    out[(size_t)NPTS * CDIM + n] = (float)bi;        // idx stored as float
}

extern "C" void kernel_launch(void* const* d_in, const int* in_sizes, int n_in,
                              void* d_out, int out_size, void* d_ws, size_t ws_size,
                              hipStream_t stream) {
    const float* enc = (const float*)d_in[0];
    const float* cb  = (const float*)d_in[1];
    float* out = (float*)d_out;

    // Workspace layout: esq[4096] | pbest[4*65536] | pidx[4*65536]  (~2.1 MB)
    float* esq   = (float*)d_ws;
    float* pbest = esq + KCODES;
    int*   pidx  = (int*)(pbest + (size_t)SPLITS * NPTS);

    vq_esq<<<KCODES / 256, 256, 0, stream>>>(cb, esq);
    dim3 grid(NPTS / 256, SPLITS);
    vq_scan<<<grid, 256, 0, stream>>>(enc, cb, esq, pbest, pidx);
    vq_finalize<<<NPTS / 256, 256, 0, stream>>>(cb, pbest, pidx, out);
}

// Round 2
// 257.245 us; speedup vs baseline: 2.3984x; 2.3984x over previous
//
#include <hip/hip_runtime.h>

// VQ-VAE quantization via bf16-MFMA prefilter + exact fp32 rescore.
// N=65536 pts, C=64, K=4096. One fused kernel: per wave = 64 points.
//   sweep1: approx max score m~ (mfma 16x16x32 bf16, acc init = -0.5*||e||^2)
//   sweep2: collect candidates with score >= m~ - DELTA into LDS list
//   rescore: exact fp32 distance for candidates, LDS atomicMin keyed
//            (ordbits(dist)<<32 | code) -> exact argmin, first-idx ties.
// DELTA=0.5 is ~12-25 sigma of the bf16 dot error -> argmin capture ~certain.

#define NPTS    65536
#define CDIM    64
#define KCODES  4096
#define LISTCAP 2048
#define DELTA   0.5f

typedef __attribute__((ext_vector_type(8))) short short8;
typedef __attribute__((ext_vector_type(4))) float f32x4;

__device__ __forceinline__ unsigned short f2bf(float x) {
    unsigned u = __float_as_uint(x);
    return (unsigned short)((u + 0x7FFFu + ((u >> 16) & 1u)) >> 16);  // RNE
}

// cb fp32 -> bf16 copy + h[k] = 0.5*||e_k||^2
__global__ __launch_bounds__(256) void vq_prep(const float* __restrict__ cb,
                                               short* __restrict__ cbb,
                                               float* __restrict__ h) {
    int k = blockIdx.x * 256 + threadIdx.x;
    const float4* p = reinterpret_cast<const float4*>(cb + (size_t)k * CDIM);
    float s0 = 0.f, s1 = 0.f, s2 = 0.f, s3 = 0.f;
#pragma unroll
    for (int i = 0; i < 16; i += 2) {
        float4 va = p[i], vb = p[i + 1];
        s0 = fmaf(va.x, va.x, s0); s1 = fmaf(va.y, va.y, s1);
        s2 = fmaf(va.z, va.z, s2); s3 = fmaf(va.w, va.w, s3);
        s0 = fmaf(vb.x, vb.x, s0); s1 = fmaf(vb.y, vb.y, s1);
        s2 = fmaf(vb.z, vb.z, s2); s3 = fmaf(vb.w, vb.w, s3);
        short8 o;
        o[0] = (short)f2bf(va.x); o[1] = (short)f2bf(va.y);
        o[2] = (short)f2bf(va.z); o[3] = (short)f2bf(va.w);
        o[4] = (short)f2bf(vb.x); o[5] = (short)f2bf(vb.y);
        o[6] = (short)f2bf(vb.z); o[7] = (short)f2bf(vb.w);
        *reinterpret_cast<short8*>(cbb + (size_t)k * CDIM + i * 4) = o;
    }
    h[k] = 0.5f * ((s0 + s1) + (s2 + s3));
}

__global__ __launch_bounds__(256) void vq_main(const float* __restrict__ enc,
                                               const float* __restrict__ cbf,
                                               const short* __restrict__ cbb,
                                               const float* __restrict__ h,
                                               float* __restrict__ out) {
    __shared__ unsigned lcnt[4];
    __shared__ unsigned list[4][LISTCAP];
    __shared__ unsigned long long mkey[4][64];

    const int tid  = threadIdx.x;
    const int wid  = tid >> 6, lane = tid & 63;
    const int lrow = lane & 15, lseg = lane >> 4;
    const int pbase = blockIdx.x * 256 + wid * 64;

    // ---- A fragments: this wave's 64 points as bf16 (resident) ----
    // 16x16x32 A layout: row = lane&15, k = (lane>>4)*8 + e (+32 per kk)
    short8 afr[4][2];
#pragma unroll
    for (int rt = 0; rt < 4; ++rt)
#pragma unroll
        for (int kk = 0; kk < 2; ++kk) {
            const float4* xp = reinterpret_cast<const float4*>(
                enc + (size_t)(pbase + rt * 16 + lrow) * CDIM + kk * 32 + lseg * 8);
            float4 v0 = xp[0], v1 = xp[1];
            short8 a;
            a[0] = (short)f2bf(v0.x); a[1] = (short)f2bf(v0.y);
            a[2] = (short)f2bf(v0.z); a[3] = (short)f2bf(v0.w);
            a[4] = (short)f2bf(v1.x); a[5] = (short)f2bf(v1.y);
            a[6] = (short)f2bf(v1.z); a[7] = (short)f2bf(v1.w);
            afr[rt][kk] = a;
        }

    if (lane == 0) lcnt[wid] = 0;
    mkey[wid][lane] = ~0ull;
    __syncthreads();

    // B tile loader: 16 codes x 64 dims bf16; per-lane 2x 16B + h dword.
    auto loadB = [&](int ct, short8& x0, short8& x1, float& hh) {
        const short* base = cbb + (size_t)(ct * 16 + lrow) * CDIM + lseg * 8;
        x0 = *reinterpret_cast<const short8*>(base);
        x1 = *reinterpret_cast<const short8*>(base + 32);
        hh = h[ct * 16 + lrow];
    };

    // ---- sweep 1: per-lane max of (dot - 0.5*esq) ----
    f32x4 best[4];
#pragma unroll
    for (int rt = 0; rt < 4; ++rt)
#pragma unroll
        for (int i = 0; i < 4; ++i) best[rt][i] = -__builtin_inff();

    short8 b0, b1; float hc;
    loadB(0, b0, b1, hc);
    for (int ct = 0; ct < KCODES / 16; ++ct) {
        short8 n0, n1; float hn;
        loadB(ct < KCODES / 16 - 1 ? ct + 1 : ct, n0, n1, hn);
        float nh = -hc;
        f32x4 acc[4];
#pragma unroll
        for (int rt = 0; rt < 4; ++rt) { acc[rt][0] = nh; acc[rt][1] = nh; acc[rt][2] = nh; acc[rt][3] = nh; }
#pragma unroll
        for (int rt = 0; rt < 4; ++rt)
            acc[rt] = __builtin_amdgcn_mfma_f32_16x16x32_bf16(afr[rt][0], b0, acc[rt], 0, 0, 0);
#pragma unroll
        for (int rt = 0; rt < 4; ++rt)
            acc[rt] = __builtin_amdgcn_mfma_f32_16x16x32_bf16(afr[rt][1], b1, acc[rt], 0, 0, 0);
#pragma unroll
        for (int rt = 0; rt < 4; ++rt)
#pragma unroll
            for (int i = 0; i < 4; ++i) best[rt][i] = fmaxf(best[rt][i], acc[rt][i]);
        b0 = n0; b1 = n1; hc = hn;
    }

    // reduce max over the 16 col-lanes of each lseg group -> m~ per row
#pragma unroll
    for (int m = 1; m <= 8; m <<= 1)
#pragma unroll
        for (int rt = 0; rt < 4; ++rt)
#pragma unroll
            for (int i = 0; i < 4; ++i)
                best[rt][i] = fmaxf(best[rt][i], __shfl_xor(best[rt][i], m, 64));
#pragma unroll
    for (int rt = 0; rt < 4; ++rt)
#pragma unroll
        for (int i = 0; i < 4; ++i) best[rt][i] -= DELTA;   // threshold

    // ---- sweep 2: identical acc; push candidates >= threshold ----
    loadB(0, b0, b1, hc);
    for (int ct = 0; ct < KCODES / 16; ++ct) {
        short8 n0, n1; float hn;
        loadB(ct < KCODES / 16 - 1 ? ct + 1 : ct, n0, n1, hn);
        float nh = -hc;
        f32x4 acc[4];
#pragma unroll
        for (int rt = 0; rt < 4; ++rt) { acc[rt][0] = nh; acc[rt][1] = nh; acc[rt][2] = nh; acc[rt][3] = nh; }
#pragma unroll
        for (int rt = 0; rt < 4; ++rt)
            acc[rt] = __builtin_amdgcn_mfma_f32_16x16x32_bf16(afr[rt][0], b0, acc[rt], 0, 0, 0);
#pragma unroll
        for (int rt = 0; rt < 4; ++rt)
            acc[rt] = __builtin_amdgcn_mfma_f32_16x16x32_bf16(afr[rt][1], b1, acc[rt], 0, 0, 0);
#pragma unroll
        for (int rt = 0; rt < 4; ++rt)
#pragma unroll
            for (int i = 0; i < 4; ++i)
                if (acc[rt][i] >= best[rt][i]) {
                    int row = rt * 16 + lseg * 4 + i;           // C/D row map (m89)
                    unsigned e = ((unsigned)row << 12) | (unsigned)(ct * 16 + lrow);
                    unsigned pos = atomicAdd(&lcnt[wid], 1u);
                    if (pos < LISTCAP) list[wid][pos] = e;
                }
        b0 = n0; b1 = n1; hc = hn;
    }
    __syncthreads();

    // ---- exact fp32 rescore of candidates ----
    unsigned cnt = lcnt[wid]; if (cnt > LISTCAP) cnt = LISTCAP;
    for (unsigned t = lane; t < cnt; t += 64) {
        unsigned e = list[wid][t];
        int row = (int)(e >> 12), c = (int)(e & 4095u);
        const float4* xp = reinterpret_cast<const float4*>(enc + (size_t)(pbase + row) * CDIM);
        const float4* ep = reinterpret_cast<const float4*>(cbf + (size_t)c * CDIM);
        float a0 = 0.f, a1 = 0.f, a2 = 0.f, a3 = 0.f;
#pragma unroll
        for (int i = 0; i < 16; ++i) {
            float4 xv = xp[i], ev = ep[i];
            a0 = fmaf(xv.x, ev.x, a0); a1 = fmaf(xv.y, ev.y, a1);
            a2 = fmaf(xv.z, ev.z, a2); a3 = fmaf(xv.w, ev.w, a3);
        }
        float dot = (a0 + a1) + (a2 + a3);
        float d2 = fmaf(-2.f, dot, 2.f * h[c]);               // esq - 2*dot
        unsigned bb = __float_as_uint(d2);
        unsigned ord = bb ^ (unsigned)(((int)bb >> 31) | 0x80000000);  // monotonic
        atomicMin(&mkey[wid][row], ((unsigned long long)ord << 32) | (unsigned)c);
    }
    __syncthreads();

    // ---- finalize: gather winner row + idx ----
    {
        int c = (int)(mkey[wid][lane] & 4095u);
        const float4* ep = reinterpret_cast<const float4*>(cbf + (size_t)c * CDIM);
        float4* op = reinterpret_cast<float4*>(out + (size_t)(pbase + lane) * CDIM);
#pragma unroll
        for (int i = 0; i < 16; ++i) op[i] = ep[i];
        out[(size_t)NPTS * CDIM + pbase + lane] = (float)c;
    }
}

extern "C" void kernel_launch(void* const* d_in, const int* in_sizes, int n_in,
                              void* d_out, int out_size, void* d_ws, size_t ws_size,
                              hipStream_t stream) {
    const float* enc = (const float*)d_in[0];
    const float* cb  = (const float*)d_in[1];
    float* out = (float*)d_out;

    // ws: cbb bf16[4096*64] (512KB) | h fp32[4096] (16KB)
    short* cbb = (short*)d_ws;
    float* hws = (float*)(cbb + (size_t)KCODES * CDIM);

    vq_prep<<<KCODES / 256, 256, 0, stream>>>(cb, cbb, hws);
    vq_main<<<NPTS / 256, 256, 0, stream>>>(enc, cb, cbb, hws, out);
}

// Round 3
// 190.303 us; speedup vs baseline: 3.2421x; 1.3518x over previous
//
#include <hip/hip_runtime.h>

// VQ-VAE quantization via bf16-MFMA prefilter + exact fp32 rescore.
// Round 3: K-split across the 4 waves of each block (occupancy 1 -> 4 waves/SIMD).
// Block = 64 points; wave w sweeps codes [w*1024, w*1024+1024).
//   sweep1: per-wave approx max score (mfma 16x16x32 bf16, acc init -0.5||e||^2)
//           -> LDS cross-wave max -> global per-row threshold m~ - DELTA
//   sweep2: identical acc; push candidates >= threshold into block LDS list
//   rescore: exact fp32 distance, LDS atomicMin (ordbits(dist)<<32 | code)
//            -> exact argmin with first-index tie-break (jnp.argmin semantics)
// DELTA=0.5 >> 2*sigma_bf16(~0.04) -> true argmin always captured.

#define NPTS    65536
#define CDIM    64
#define KCODES  4096
#define WAVES   4
#define KPW     (KCODES / WAVES)   // 1024 codes per wave
#define TILES   (KPW / 16)         // 64 B-tiles of 16 codes
#define LISTCAP 4096
#define DELTA   0.5f

typedef __attribute__((ext_vector_type(8))) short short8;
typedef __attribute__((ext_vector_type(4))) float f32x4;

__device__ __forceinline__ unsigned short f2bf(float x) {
    unsigned u = __float_as_uint(x);
    return (unsigned short)((u + 0x7FFFu + ((u >> 16) & 1u)) >> 16);  // RNE
}

// cb fp32 -> bf16 copy + h[k] = 0.5*||e_k||^2
__global__ __launch_bounds__(256) void vq_prep(const float* __restrict__ cb,
                                               short* __restrict__ cbb,
                                               float* __restrict__ h) {
    int k = blockIdx.x * 256 + threadIdx.x;
    const float4* p = reinterpret_cast<const float4*>(cb + (size_t)k * CDIM);
    float s0 = 0.f, s1 = 0.f, s2 = 0.f, s3 = 0.f;
#pragma unroll
    for (int i = 0; i < 16; i += 2) {
        float4 va = p[i], vb = p[i + 1];
        s0 = fmaf(va.x, va.x, s0); s1 = fmaf(va.y, va.y, s1);
        s2 = fmaf(va.z, va.z, s2); s3 = fmaf(va.w, va.w, s3);
        s0 = fmaf(vb.x, vb.x, s0); s1 = fmaf(vb.y, vb.y, s1);
        s2 = fmaf(vb.z, vb.z, s2); s3 = fmaf(vb.w, vb.w, s3);
        short8 o;
        o[0] = (short)f2bf(va.x); o[1] = (short)f2bf(va.y);
        o[2] = (short)f2bf(va.z); o[3] = (short)f2bf(va.w);
        o[4] = (short)f2bf(vb.x); o[5] = (short)f2bf(vb.y);
        o[6] = (short)f2bf(vb.z); o[7] = (short)f2bf(vb.w);
        *reinterpret_cast<short8*>(cbb + (size_t)k * CDIM + i * 4) = o;
    }
    h[k] = 0.5f * ((s0 + s1) + (s2 + s3));
}

__global__ __launch_bounds__(256) void vq_main(const float* __restrict__ enc,
                                               const float* __restrict__ cbf,
                                               const short* __restrict__ cbb,
                                               const float* __restrict__ h,
                                               float* __restrict__ out) {
    __shared__ unsigned lcnt;
    __shared__ unsigned list[LISTCAP];
    __shared__ float rowmax[WAVES][64];
    __shared__ unsigned long long mkey[64];

    const int tid  = threadIdx.x;
    const int wid  = tid >> 6, lane = tid & 63;
    const int lrow = lane & 15, lseg = lane >> 4;
    const int pbase = blockIdx.x * 64;     // 64 points per block
    const int k0 = wid * KPW;              // this wave's code slice

    if (tid == 0) lcnt = 0;
    if (tid < 64) mkey[tid] = ~0ull;

    // ---- A fragments: the block's 64 points as bf16 (all waves identical) ----
    // 16x16x32 A layout: row = lane&15, k = (lane>>4)*8 + e (+32 per kk)
    short8 afr[4][2];
#pragma unroll
    for (int rt = 0; rt < 4; ++rt)
#pragma unroll
        for (int kk = 0; kk < 2; ++kk) {
            const float4* xp = reinterpret_cast<const float4*>(
                enc + (size_t)(pbase + rt * 16 + lrow) * CDIM + kk * 32 + lseg * 8);
            float4 v0 = xp[0], v1 = xp[1];
            short8 a;
            a[0] = (short)f2bf(v0.x); a[1] = (short)f2bf(v0.y);
            a[2] = (short)f2bf(v0.z); a[3] = (short)f2bf(v0.w);
            a[4] = (short)f2bf(v1.x); a[5] = (short)f2bf(v1.y);
            a[6] = (short)f2bf(v1.z); a[7] = (short)f2bf(v1.w);
            afr[rt][kk] = a;
        }

    // B tile loader: 16 codes x 64 dims bf16; per-lane 2x 16B + h dword.
    auto loadB = [&](int ct, short8& x0, short8& x1, float& hh) {
        int code = k0 + ct * 16 + lrow;
        const short* base = cbb + (size_t)code * CDIM + lseg * 8;
        x0 = *reinterpret_cast<const short8*>(base);
        x1 = *reinterpret_cast<const short8*>(base + 32);
        hh = h[code];
    };

    // ---- sweep 1: per-lane max of (dot - 0.5*esq) over this wave's slice ----
    f32x4 best[4];
#pragma unroll
    for (int rt = 0; rt < 4; ++rt)
#pragma unroll
        for (int i = 0; i < 4; ++i) best[rt][i] = -__builtin_inff();

    short8 b0, b1; float hc;
    loadB(0, b0, b1, hc);
    for (int ct = 0; ct < TILES; ++ct) {
        short8 n0, n1; float hn;
        loadB(ct < TILES - 1 ? ct + 1 : ct, n0, n1, hn);
        float nh = -hc;
        f32x4 acc[4];
#pragma unroll
        for (int rt = 0; rt < 4; ++rt) { acc[rt][0] = nh; acc[rt][1] = nh; acc[rt][2] = nh; acc[rt][3] = nh; }
#pragma unroll
        for (int rt = 0; rt < 4; ++rt)
            acc[rt] = __builtin_amdgcn_mfma_f32_16x16x32_bf16(afr[rt][0], b0, acc[rt], 0, 0, 0);
#pragma unroll
        for (int rt = 0; rt < 4; ++rt)
            acc[rt] = __builtin_amdgcn_mfma_f32_16x16x32_bf16(afr[rt][1], b1, acc[rt], 0, 0, 0);
#pragma unroll
        for (int rt = 0; rt < 4; ++rt)
#pragma unroll
            for (int i = 0; i < 4; ++i) best[rt][i] = fmaxf(best[rt][i], acc[rt][i]);
        b0 = n0; b1 = n1; hc = hn;
    }

    // intra-wave max over the 16 col-lanes (lrow dimension)
#pragma unroll
    for (int m = 1; m <= 8; m <<= 1)
#pragma unroll
        for (int rt = 0; rt < 4; ++rt)
#pragma unroll
            for (int i = 0; i < 4; ++i)
                best[rt][i] = fmaxf(best[rt][i], __shfl_xor(best[rt][i], m, 64));

    // cross-wave max via LDS
    if (lrow == 0) {
#pragma unroll
        for (int rt = 0; rt < 4; ++rt)
#pragma unroll
            for (int i = 0; i < 4; ++i)
                rowmax[wid][rt * 16 + lseg * 4 + i] = best[rt][i];
    }
    __syncthreads();
#pragma unroll
    for (int rt = 0; rt < 4; ++rt)
#pragma unroll
        for (int i = 0; i < 4; ++i) {
            int row = rt * 16 + lseg * 4 + i;
            float m0 = fmaxf(rowmax[0][row], rowmax[1][row]);
            float m1 = fmaxf(rowmax[2][row], rowmax[3][row]);
            best[rt][i] = fmaxf(m0, m1) - DELTA;   // global threshold
        }

    // ---- sweep 2: identical acc; push candidates >= threshold ----
    loadB(0, b0, b1, hc);
    for (int ct = 0; ct < TILES; ++ct) {
        short8 n0, n1; float hn;
        loadB(ct < TILES - 1 ? ct + 1 : ct, n0, n1, hn);
        float nh = -hc;
        f32x4 acc[4];
#pragma unroll
        for (int rt = 0; rt < 4; ++rt) { acc[rt][0] = nh; acc[rt][1] = nh; acc[rt][2] = nh; acc[rt][3] = nh; }
#pragma unroll
        for (int rt = 0; rt < 4; ++rt)
            acc[rt] = __builtin_amdgcn_mfma_f32_16x16x32_bf16(afr[rt][0], b0, acc[rt], 0, 0, 0);
#pragma unroll
        for (int rt = 0; rt < 4; ++rt)
            acc[rt] = __builtin_amdgcn_mfma_f32_16x16x32_bf16(afr[rt][1], b1, acc[rt], 0, 0, 0);
#pragma unroll
        for (int rt = 0; rt < 4; ++rt)
#pragma unroll
            for (int i = 0; i < 4; ++i)
                if (acc[rt][i] >= best[rt][i]) {
                    int row = rt * 16 + lseg * 4 + i;           // C/D row map (m89)
                    unsigned e = ((unsigned)row << 12) | (unsigned)(k0 + ct * 16 + lrow);
                    unsigned pos = atomicAdd(&lcnt, 1u);
                    if (pos < LISTCAP) list[pos] = e;
                }
        b0 = n0; b1 = n1; hc = hn;
    }
    __syncthreads();

    // ---- exact fp32 rescore of candidates (block-wide) ----
    unsigned cnt = lcnt; if (cnt > LISTCAP) cnt = LISTCAP;
    for (unsigned t = tid; t < cnt; t += 256) {
        unsigned e = list[t];
        int row = (int)(e >> 12), c = (int)(e & 4095u);
        const float4* xp = reinterpret_cast<const float4*>(enc + (size_t)(pbase + row) * CDIM);
        const float4* ep = reinterpret_cast<const float4*>(cbf + (size_t)c * CDIM);
        float a0 = 0.f, a1 = 0.f, a2 = 0.f, a3 = 0.f;
#pragma unroll
        for (int i = 0; i < 16; ++i) {
            float4 xv = xp[i], ev = ep[i];
            a0 = fmaf(xv.x, ev.x, a0); a1 = fmaf(xv.y, ev.y, a1);
            a2 = fmaf(xv.z, ev.z, a2); a3 = fmaf(xv.w, ev.w, a3);
        }
        float dot = (a0 + a1) + (a2 + a3);
        float d2 = fmaf(-2.f, dot, 2.f * h[c]);               // esq - 2*dot
        unsigned bb = __float_as_uint(d2);
        unsigned ord = bb ^ (unsigned)(((int)bb >> 31) | 0x80000000);  // monotonic
        atomicMin(&mkey[row], ((unsigned long long)ord << 32) | (unsigned)c);
    }
    __syncthreads();

    // ---- finalize: gather winner rows (4 threads per point) + idx ----
    {
        int p = tid >> 2, q = tid & 3;
        int c = (int)(mkey[p] & 4095u);
        const float4* ep = reinterpret_cast<const float4*>(cbf + (size_t)c * CDIM) + q * 4;
        float4* op = reinterpret_cast<float4*>(out + (size_t)(pbase + p) * CDIM) + q * 4;
#pragma unroll
        for (int i = 0; i < 4; ++i) op[i] = ep[i];
        if (tid < 64)
            out[(size_t)NPTS * CDIM + pbase + tid] = (float)(mkey[tid] & 4095u);
    }
}

extern "C" void kernel_launch(void* const* d_in, const int* in_sizes, int n_in,
                              void* d_out, int out_size, void* d_ws, size_t ws_size,
                              hipStream_t stream) {
    const float* enc = (const float*)d_in[0];
    const float* cb  = (const float*)d_in[1];
    float* out = (float*)d_out;

    // ws: cbb bf16[4096*64] (512KB) | h fp32[4096] (16KB)
    short* cbb = (short*)d_ws;
    float* hws = (float*)(cbb + (size_t)KCODES * CDIM);

    vq_prep<<<KCODES / 256, 256, 0, stream>>>(cb, cbb, hws);
    vq_main<<<NPTS / 64, 256, 0, stream>>>(enc, cb, cbb, hws, out);
}